// Round 8
// baseline (361.623 us; speedup 1.0000x reference)
//
#include <hip/hip_runtime.h>
#include <stdint.h>

// B=1024, T=65, D=H=512. Only the SLOW critic feeds the output.
//   prep:  W1s,W2s -> bf16 transposed Wt[n][k]; zero tarval
//   gemm1: H1 = silu(feat @ W1s + b1s)           BK=64 dbuf, pa 2-deep
//   gemm2: tarval = silu(H1 @ W2s + b2s) @ W3s   BK=64 dbuf all-gload 2-deep
//   scan:  lambda-return suffix scan (log-depth shuffle) -> out (f32)
// Key fix vs r6: vmcnt is IN-ORDER, so the A(feat) reg-loads must issue a
// full iter earlier than their ds_write or the implicit wait exposes HBM
// latency every K-step. pa[2] banks: load tile t+2 at top of iter t, write
// tile t+1 (loaded 1.25 iters ago) at mid of iter t.

#define MROWS 66560   // 1024*65
#define RBLK 520      // MROWS/128
#define LAMF 0.95f
#define DISCF ((float)(1.0 - 1.0 / 333.0))

typedef __attribute__((ext_vector_type(8))) __bf16 bf16x8;
typedef __attribute__((ext_vector_type(4))) float f32x4;
typedef __attribute__((ext_vector_type(4))) unsigned int u32x4;

__device__ __forceinline__ unsigned short f2bf(float f) {
  unsigned int u = __float_as_uint(f);
  return (unsigned short)((u + 0x7FFFu + ((u >> 16) & 1u)) >> 16);
}
__device__ __forceinline__ float silu_f(float x) { return x / (1.0f + __expf(-x)); }

__device__ __forceinline__ void gload_lds16(const void* g, void* l) {
  __builtin_amdgcn_global_load_lds(
      (const __attribute__((address_space(1))) void*)g,
      (__attribute__((address_space(3))) void*)l, 16, 0, 0);
}

// compiler emits v_cvt_pk_bf16_f32 pairs (RNE)
__device__ __forceinline__ u32x4 pack8(const f32x4& a, const f32x4& b) {
  union { __bf16 h[8]; u32x4 u; } p;
  p.h[0] = (__bf16)a[0]; p.h[1] = (__bf16)a[1];
  p.h[2] = (__bf16)a[2]; p.h[3] = (__bf16)a[3];
  p.h[4] = (__bf16)b[0]; p.h[5] = (__bf16)b[1];
  p.h[6] = (__bf16)b[2]; p.h[7] = (__bf16)b[3];
  return p.u;
}
__device__ __forceinline__ unsigned short f2bfc(float f) {
  union { __bf16 h; unsigned short s; } u; u.h = (__bf16)f; return u.s;
}

// ---------------- prep: tiled transpose W->Wt bf16, zero tarval --------------
__global__ __launch_bounds__(256) void prep_kernel(
    const float* __restrict__ W1, const float* __restrict__ W2,
    unsigned short* __restrict__ Wt1, unsigned short* __restrict__ Wt2,
    float* __restrict__ tarval) {
  int b = blockIdx.x;
  if (b < 128) {
    const float* W = (b < 64) ? W1 : W2;
    unsigned short* Wt = (b < 64) ? Wt1 : Wt2;
    int tb = b & 63;
    int tk = (tb >> 3) * 64;
    int tn = (tb & 7) * 64;
    __shared__ float tile[64][65];
    int tx = threadIdx.x & 63;
    int ty4 = threadIdx.x >> 6;
#pragma unroll
    for (int i = 0; i < 16; ++i) {
      int row = ty4 * 16 + i;
      tile[row][tx] = W[(size_t)(tk + row) * 512 + tn + tx];
    }
    __syncthreads();
#pragma unroll
    for (int i = 0; i < 16; ++i) {
      int nrow = ty4 * 16 + i;
      Wt[(size_t)(tn + nrow) * 512 + tk + tx] = f2bf(tile[tx][nrow]);
    }
  } else {
    int id = (b - 128) * 256 + threadIdx.x;
#pragma unroll
    for (int i = 0; i < 17; ++i) {
      int idx = id + i * 4096;
      if (idx < MROWS) tarval[idx] = 0.0f;
    }
  }
}

// XCD-aware tile mapping: 4 col-blocks of one row-tile are consecutive per-XCD.
__device__ __forceinline__ void tile_map(int bid, int& rb, int& cb) {
  int xcd = bid & 7;
  int idx = bid >> 3;
  rb = xcd * 65 + (idx >> 2);
  cb = idx & 3;
}

// ---------------- GEMM1: A=feat f32 (reg convert, 2-deep), B=Wt1 bf16 -------
__global__ __launch_bounds__(256) void gemm1_kernel(
    const float* __restrict__ A, const unsigned short* __restrict__ Bt,
    const float* __restrict__ bias, unsigned short* __restrict__ Hout) {
  __shared__ __align__(16) unsigned char lds[65536];  // [2][A 16K | B 16K]

  int rb, cb; tile_map(blockIdx.x, rb, cb);
  const int m0 = rb * 128, n0 = cb * 128;
  const int tid = threadIdx.x;
  const int lane = tid & 63, w = tid >> 6;
  const int wr = w >> 1, wc = w & 1;
  const int q = lane >> 4, r = lane & 15;
  const unsigned int rx = (unsigned)(r & 7) << 4;          // read-side swizzle

  f32x4 acc[4][4] = {};
  f32x4 pa[2][8];                                          // 2 banks, 2-deep

  // A reg-path source coords (unswizzled) + swizzled ds_write dest XOR
  const int a_row_off = tid >> 3;                          // + i*32
  const int a_col = (tid & 7) * 8;
  const unsigned int awx = ((unsigned)((tid >> 3) & 7)) << 4;
  // B gload path: linear dest, pre-swizzled global source
  const int b_row_off = w * 8 + (lane >> 3);               // + i*32
  const int b_col = ((lane & 7) ^ (lane >> 3)) * 8;

  // ---- prologue: pa0<-tile0; B(0)->bufB0; pa1<-tile1; B(1)->bufB1;
  //                write pa0 -> bufA0 (implicit counted wait, retires pa0 only)
#pragma unroll
  for (int i = 0; i < 4; ++i) {
    const float* s = A + (size_t)(m0 + i * 32 + a_row_off) * 512 + a_col;
    pa[0][2 * i] = *(const f32x4*)s; pa[0][2 * i + 1] = *(const f32x4*)(s + 4);
  }
#pragma unroll
  for (int i = 0; i < 4; ++i)
    gload_lds16(Bt + (size_t)(n0 + i * 32 + b_row_off) * 512 + b_col,
                lds + 16384 + i * 4096 + w * 1024);
#pragma unroll
  for (int i = 0; i < 4; ++i) {
    const float* s = A + (size_t)(m0 + i * 32 + a_row_off) * 512 + 64 + a_col;
    pa[1][2 * i] = *(const f32x4*)s; pa[1][2 * i + 1] = *(const f32x4*)(s + 4);
  }
#pragma unroll
  for (int i = 0; i < 4; ++i)
    gload_lds16(Bt + (size_t)(n0 + i * 32 + b_row_off) * 512 + 64 + b_col,
                lds + 49152 + i * 4096 + w * 1024);
#pragma unroll
  for (int i = 0; i < 4; ++i)
    *(u32x4*)(lds + ((unsigned)(i * 4096 + tid * 16) ^ awx)) =
        pack8(pa[0][2 * i], pa[0][2 * i + 1]);

#pragma unroll
  for (int t = 0; t < 8; ++t) {
    if (t < 7) asm volatile("s_waitcnt vmcnt(8) lgkmcnt(0)" ::: "memory");
    else       asm volatile("s_waitcnt vmcnt(0) lgkmcnt(0)" ::: "memory");
    __builtin_amdgcn_s_barrier();

    unsigned char* Acur = lds + (t & 1) * 32768;
    unsigned char* Bcur = Acur + 16384;

    if (t + 2 < 8) {      // pa[t&1] <- tile t+2 (written at mid of iter t+1)
      const int ks = (t + 2) * 64;
#pragma unroll
      for (int i = 0; i < 4; ++i) {
        const float* s = A + (size_t)(m0 + i * 32 + a_row_off) * 512 + ks + a_col;
        pa[t & 1][2 * i] = *(const f32x4*)s;
        pa[t & 1][2 * i + 1] = *(const f32x4*)(s + 4);
      }
    }

    // fragment reads (swizzled) -> regs
    bf16x8 af[2][4], bfr[2][4];
#pragma unroll
    for (int kk = 0; kk < 2; ++kk) {
      const unsigned int kb = kk * 64 + q * 16;
#pragma unroll
      for (int m = 0; m < 4; ++m) {
        const unsigned int row = wr * 64 + m * 16 + r;
        af[kk][m] = *(const bf16x8*)(Acur + ((row * 128 + kb) ^ rx));
      }
#pragma unroll
      for (int n = 0; n < 4; ++n) {
        const unsigned int row = wc * 64 + n * 16 + r;
        bfr[kk][n] = *(const bf16x8*)(Bcur + ((row * 128 + kb) ^ rx));
      }
    }
    asm volatile("s_waitcnt lgkmcnt(0)" ::: "memory");
    __builtin_amdgcn_sched_barrier(0);
    __builtin_amdgcn_s_barrier();     // all waves done reading buf[t&1]

    if (t + 2 < 8) {                  // B(t+2) -> bufB[t&1] (2-ahead, counted)
      const int ks = (t + 2) * 64;
#pragma unroll
      for (int i = 0; i < 4; ++i)
        gload_lds16(Bt + (size_t)(n0 + i * 32 + b_row_off) * 512 + ks + b_col,
                    Bcur + i * 4096 + w * 1024);
    }
    if (t < 7) {   // write pa[(t+1)&1] (tile t+1, loaded 1.25 iters ago)
      unsigned char* Anx = lds + ((t + 1) & 1) * 32768;
#pragma unroll
      for (int i = 0; i < 4; ++i)
        *(u32x4*)(Anx + ((unsigned)(i * 4096 + tid * 16) ^ awx)) =
            pack8(pa[(t + 1) & 1][2 * i], pa[(t + 1) & 1][2 * i + 1]);
    }

#pragma unroll
    for (int kk = 0; kk < 2; ++kk)
#pragma unroll
      for (int m = 0; m < 4; ++m)
#pragma unroll
        for (int n = 0; n < 4; ++n)
          acc[m][n] = __builtin_amdgcn_mfma_f32_16x16x32_bf16(af[kk][m], bfr[kk][n], acc[m][n], 0, 0, 0);
  }

  // epilogue: bias + silu -> bf16 H1
#pragma unroll
  for (int n = 0; n < 4; ++n) {
    const int col = n0 + wc * 64 + n * 16 + r;
    const float bn = bias[col];
#pragma unroll
    for (int m = 0; m < 4; ++m) {
      const int rbase = m0 + wr * 64 + m * 16 + q * 4;
#pragma unroll
      for (int i = 0; i < 4; ++i)
        Hout[(size_t)(rbase + i) * 512 + col] = f2bfc(silu_f(acc[m][n][i] + bn));
    }
  }
}

// ---------------- GEMM2: A=H1 bf16, B=Wt2 bf16, fused W3 reduce -------------
__global__ __launch_bounds__(256) void gemm2_kernel(
    const unsigned short* __restrict__ A, const unsigned short* __restrict__ Bt,
    const float* __restrict__ bias, const float* __restrict__ W3,
    float* __restrict__ tarval) {
  __shared__ __align__(16) unsigned char lds[65536];

  int rb, cb; tile_map(blockIdx.x, rb, cb);
  const int m0 = rb * 128, n0 = cb * 128;
  const int tid = threadIdx.x;
  const int lane = tid & 63, w = tid >> 6;
  const int wr = w >> 1, wc = w & 1;
  const int q = lane >> 4, r = lane & 15;
  const unsigned int rx = (unsigned)(r & 7) << 4;

  f32x4 acc[4][4] = {};
  const int s_row_off = w * 8 + (lane >> 3);                // + i*32
  const int s_col = ((lane & 7) ^ (lane >> 3)) * 8;

  // ---- prologue: stage(0)->buf0, stage(1)->buf1 (8 gloads each) ----
#pragma unroll
  for (int i = 0; i < 4; ++i) {
    gload_lds16(A  + (size_t)(m0 + i * 32 + s_row_off) * 512 + s_col,
                lds + i * 4096 + w * 1024);
    gload_lds16(Bt + (size_t)(n0 + i * 32 + s_row_off) * 512 + s_col,
                lds + 16384 + i * 4096 + w * 1024);
  }
#pragma unroll
  for (int i = 0; i < 4; ++i) {
    gload_lds16(A  + (size_t)(m0 + i * 32 + s_row_off) * 512 + 64 + s_col,
                lds + 32768 + i * 4096 + w * 1024);
    gload_lds16(Bt + (size_t)(n0 + i * 32 + s_row_off) * 512 + 64 + s_col,
                lds + 49152 + i * 4096 + w * 1024);
  }

#pragma unroll
  for (int t = 0; t < 8; ++t) {
    if (t < 7) asm volatile("s_waitcnt vmcnt(8) lgkmcnt(0)" ::: "memory");
    else       asm volatile("s_waitcnt vmcnt(0) lgkmcnt(0)" ::: "memory");
    __builtin_amdgcn_s_barrier();

    unsigned char* Acur = lds + (t & 1) * 32768;
    unsigned char* Bcur = Acur + 16384;

    bf16x8 af[2][4], bfr[2][4];
#pragma unroll
    for (int kk = 0; kk < 2; ++kk) {
      const unsigned int kb = kk * 64 + q * 16;
#pragma unroll
      for (int m = 0; m < 4; ++m) {
        const unsigned int row = wr * 64 + m * 16 + r;
        af[kk][m] = *(const bf16x8*)(Acur + ((row * 128 + kb) ^ rx));
      }
#pragma unroll
      for (int n = 0; n < 4; ++n) {
        const unsigned int row = wc * 64 + n * 16 + r;
        bfr[kk][n] = *(const bf16x8*)(Bcur + ((row * 128 + kb) ^ rx));
      }
    }
    asm volatile("s_waitcnt lgkmcnt(0)" ::: "memory");
    __builtin_amdgcn_sched_barrier(0);
    __builtin_amdgcn_s_barrier();

    if (t + 2 < 8) {                  // stage(t+2) -> buf[t&1]
      const int ks = (t + 2) * 64;
#pragma unroll
      for (int i = 0; i < 4; ++i) {
        gload_lds16(A  + (size_t)(m0 + i * 32 + s_row_off) * 512 + ks + s_col,
                    Acur + i * 4096 + w * 1024);
        gload_lds16(Bt + (size_t)(n0 + i * 32 + s_row_off) * 512 + ks + s_col,
                    Bcur + i * 4096 + w * 1024);
      }
    }

#pragma unroll
    for (int kk = 0; kk < 2; ++kk)
#pragma unroll
      for (int m = 0; m < 4; ++m)
#pragma unroll
        for (int n = 0; n < 4; ++n)
          acc[m][n] = __builtin_amdgcn_mfma_f32_16x16x32_bf16(af[kk][m], bfr[kk][n], acc[m][n], 0, 0, 0);
  }

  // epilogue: silu(acc+b2) * W3[col], 16-lane shuffle reduce, atomic per row
#pragma unroll
  for (int m = 0; m < 4; ++m) {
    float ps0 = 0.f, ps1 = 0.f, ps2 = 0.f, ps3 = 0.f;
#pragma unroll
    for (int n = 0; n < 4; ++n) {
      const int col = n0 + wc * 64 + n * 16 + r;
      const float bn = bias[col];
      const float w3 = W3[col];
      ps0 += silu_f(acc[m][n][0] + bn) * w3;
      ps1 += silu_f(acc[m][n][1] + bn) * w3;
      ps2 += silu_f(acc[m][n][2] + bn) * w3;
      ps3 += silu_f(acc[m][n][3] + bn) * w3;
    }
    float ps[4] = {ps0, ps1, ps2, ps3};
#pragma unroll
    for (int i = 0; i < 4; ++i) {
      float v = ps[i];
      v += __shfl_xor(v, 1);
      v += __shfl_xor(v, 2);
      v += __shfl_xor(v, 4);
      v += __shfl_xor(v, 8);
      if (r == 0) {
        int row = m0 + wr * 64 + m * 16 + q * 4 + i;
        atomicAdd(&tarval[row], v);
      }
    }
  }
}

// ------- scan: suffix-composition lambda-return, log-depth shuffle ----------
// r_t = i_t + c_t * r_{t+1}; compose (i1,c1)o(i2,c2) = (i1 + c1*i2, c1*c2)
__global__ __launch_bounds__(256) void scan_kernel(
    const float* __restrict__ tarval, const float* __restrict__ reward,
    const float* __restrict__ cont, const float* __restrict__ voffset,
    const float* __restrict__ vscale, const float* __restrict__ b3,
    float* __restrict__ out) {
  const int row = blockIdx.x * 4 + (threadIdx.x >> 6);  // one wave per batch row
  const int t = threadIdx.x & 63;                       // maps to orig t+1
  const float vs = vscale[0], vo = voffset[0], bb = b3[0];
  const int g = row * 65 + 1 + t;
  const float tv = (tarval[g] + bb) * vs + vo;
  const float dt = cont[g] * DISCF;
  float ci = reward[g] + (1.0f - LAMF) * dt * tv;
  float cc = dt * LAMF;
  const float boot = __shfl(tv, 63, 64);
#pragma unroll
  for (int off = 1; off < 64; off <<= 1) {
    float i2 = __shfl_down(ci, off, 64);
    float c2 = __shfl_down(cc, off, 64);
    if (t + off < 64) { ci = ci + cc * i2; cc = cc * c2; }
  }
  out[row * 64 + t] = ci + cc * boot;
}

extern "C" void kernel_launch(void* const* d_in, const int* in_sizes, int n_in,
                              void* d_out, int out_size, void* d_ws, size_t ws_size,
                              hipStream_t stream) {
  const float* feat    = (const float*)d_in[0];
  const float* reward  = (const float*)d_in[1];
  const float* cont    = (const float*)d_in[2];
  const float* voffset = (const float*)d_in[3];
  const float* vscale  = (const float*)d_in[4];
  const float* W1s = (const float*)d_in[11];
  const float* b1s = (const float*)d_in[12];
  const float* W2s = (const float*)d_in[13];
  const float* b2s = (const float*)d_in[14];
  const float* W3s = (const float*)d_in[15];
  const float* b3s = (const float*)d_in[16];

  char* ws = (char*)d_ws;
  unsigned short* Wt1 = (unsigned short*)ws;                   // 512 KB
  unsigned short* Wt2 = (unsigned short*)(ws + (512u << 10));  // 512 KB
  float* tarval       = (float*)(ws + (1024u << 10));          // 266 240 B
  unsigned short* H1  = (unsigned short*)(ws + (2048u << 10)); // 68 157 440 B

  prep_kernel<<<144, 256, 0, stream>>>(W1s, W2s, Wt1, Wt2, tarval);
  gemm1_kernel<<<RBLK * 4, 256, 0, stream>>>(feat, Wt1, b1s, H1);
  gemm2_kernel<<<RBLK * 4, 256, 0, stream>>>(H1, Wt2, b2s, W3s, tarval);
  scan_kernel<<<256, 256, 0, stream>>>(tarval, reward, cont, voffset, vscale, b3s,
                                       (float*)d_out);
}